// Round 1
// baseline (32980.911 us; speedup 1.0000x reference)
//
#include <hip/hip_runtime.h>
#include <math.h>

#define NCLS 80
#define KTOP 1000
#define SCORE_T 0.05f
#define NMS_T 0.6f
#define SCALE_CLAMP 4.135166556742356f
#define IMGW 1344.0f
#define IMGH 1024.0f

// ----------------------------------------------------------------------------
// generic 3x3 same-pad conv, Cin=256. Block: 256 thr -> 64 couts x (8x16) tile.
// Each thread: 4 couts x (2x4) positions.
// ----------------------------------------------------------------------------
template<int RELU>
__global__ __launch_bounds__(256)
void conv3x3(const float* __restrict__ in, const float* __restrict__ wt,
             const float* __restrict__ bias, float* __restrict__ out,
             int H, int W, int Cout, int tilesX)
{
    __shared__ float sP[4][10][18];
    __shared__ float sW[64][37];
    const int tid  = threadIdx.x;
    const int tile = blockIdx.x;
    const int n    = blockIdx.y;
    const int cout0 = blockIdx.z * 64;
    const int ty = tile / tilesX, tx = tile % tilesX;
    const int h0 = ty * 8, w0 = tx * 16;
    const int cell = tid & 15, cg = tid >> 4;
    const int pr = (cell >> 2) << 1;   // 0,2,4,6
    const int pc = (cell & 3) << 2;    // 0,4,8,12
    const int HW = H * W;
    const float* inN = in + (size_t)n * 256 * HW;

    float acc[4][8];
#pragma unroll
    for (int a = 0; a < 4; ++a)
#pragma unroll
        for (int b = 0; b < 8; ++b) acc[a][b] = 0.f;

    for (int ci0 = 0; ci0 < 256; ci0 += 4) {
        for (int e = tid; e < 720; e += 256) {
            int ci = e / 180, r = e % 180;
            int rr = r / 18, cc2 = r % 18;
            int gh = h0 + rr - 1, gw = w0 + cc2 - 1;
            float v = 0.f;
            if ((unsigned)gh < (unsigned)H && (unsigned)gw < (unsigned)W)
                v = inN[(size_t)(ci0 + ci) * HW + gh * W + gw];
            sP[ci][rr][cc2] = v;
        }
        for (int e = tid; e < 2304; e += 256) {
            int c = e / 36, r = e % 36;
            int gc = cout0 + c;
            float v = (gc < Cout) ? wt[((size_t)gc * 256 + (ci0 + r / 9)) * 9 + (r % 9)] : 0.f;
            sW[c][r] = v;
        }
        __syncthreads();
#pragma unroll
        for (int ci = 0; ci < 4; ++ci) {
            float x[4][6];
#pragma unroll
            for (int r = 0; r < 4; ++r)
#pragma unroll
                for (int c2 = 0; c2 < 6; ++c2) x[r][c2] = sP[ci][pr + r][pc + c2];
#pragma unroll
            for (int cc = 0; cc < 4; ++cc) {
                float wv[9];
#pragma unroll
                for (int k = 0; k < 9; ++k) wv[k] = sW[cg * 4 + cc][ci * 9 + k];
#pragma unroll
                for (int py = 0; py < 2; ++py)
#pragma unroll
                    for (int px = 0; px < 4; ++px) {
                        float s = acc[cc][py * 4 + px];
#pragma unroll
                        for (int dy = 0; dy < 3; ++dy)
#pragma unroll
                            for (int dx = 0; dx < 3; ++dx)
                                s = fmaf(wv[dy * 3 + dx], x[py + dy][px + dx], s);
                        acc[cc][py * 4 + px] = s;
                    }
            }
        }
        __syncthreads();
    }
#pragma unroll
    for (int cc = 0; cc < 4; ++cc) {
        int gc = cout0 + cg * 4 + cc;
        if (gc >= Cout) continue;
        float b = bias[gc];
        float* outc = out + ((size_t)n * Cout + gc) * HW;
#pragma unroll
        for (int py = 0; py < 2; ++py) {
            int gh = h0 + pr + py;
            if (gh >= H) continue;
#pragma unroll
            for (int px = 0; px < 4; ++px) {
                int gw = w0 + pc + px;
                if (gw >= W) continue;
                float v = acc[cc][py * 4 + px] + b;
                if (RELU) v = fmaxf(v, 0.f);
                outc[gh * W + gw] = v;
            }
        }
    }
}

// ----------------------------------------------------------------------------
__global__ void pack_kernel(const float* __restrict__ sw, const float* __restrict__ sb,
                            const float* __restrict__ cw, const float* __restrict__ cb,
                            float* __restrict__ pw, float* __restrict__ pb)
{
    int i = blockIdx.x * 256 + threadIdx.x;
    const int tot = 81 * 2304;
    if (i < tot) pw[i] = (i < 80 * 2304) ? sw[i] : cw[i - 80 * 2304];
    if (i < 81)  pb[i] = (i < 80) ? sb[i] : cb[i - 80];
}

// ----------------------------------------------------------------------------
__global__ __launch_bounds__(256)
void score_kernel(const float* __restrict__ lg, float* __restrict__ scores, int HW)
{
    __shared__ float tile[64 * 81];
    __shared__ float sctr[64];
    int n = blockIdx.y;
    int pos0 = blockIdx.x * 64;
    int tid = threadIdx.x;
    const float* L = lg + (size_t)n * 81 * HW;
    if (tid < 64) {
        int p = pos0 + tid;
        float c = (p < HW) ? L[(size_t)80 * HW + p] : 0.f;
        sctr[tid] = 1.f / (1.f + expf(-c));
    }
    __syncthreads();
    for (int e = tid; e < 64 * NCLS; e += 256) {
        int c = e >> 6;
        int p = e & 63;
        int gp = pos0 + p;
        float l = (gp < HW) ? L[(size_t)c * HW + gp] : 0.f;
        float sl = 1.f / (1.f + expf(-l));
        tile[p * 81 + c] = sqrtf(sl * sctr[p]);
    }
    __syncthreads();
    float* dst = scores + (size_t)n * HW * NCLS + (size_t)pos0 * NCLS;
    int valid = HW - pos0; if (valid > 64) valid = 64;
    int lim = valid * NCLS;
    for (int e = tid; e < lim; e += 256) dst[e] = tile[(e / 80) * 81 + e % 80];
}

// ----------------------------------------------------------------------------
__global__ __launch_bounds__(256)
void hist_kernel(const float* __restrict__ scores, unsigned* __restrict__ hist,
                 const int* __restrict__ sel, int nElems, int pass)
{
    __shared__ unsigned h[4096];
    int n = blockIdx.y;
    const float* S = scores + (size_t)n * nElems;
    unsigned* H = hist + n * 4096;
    const int* SL = sel + n * 8;
    for (int i = threadIdx.x; i < 4096; i += 256) h[i] = 0;
    __syncthreads();
    unsigned b1 = 0, b2 = 0;
    if (pass >= 1) b1 = (unsigned)SL[0];
    if (pass == 2) b2 = (unsigned)SL[2];
    int stride = gridDim.x * 256;
    for (int i = blockIdx.x * 256 + threadIdx.x; i < nElems; i += stride) {
        unsigned bits = __float_as_uint(S[i]);
        if (pass == 0) atomicAdd(&h[bits >> 24], 1u);
        else if (pass == 1) { if ((bits >> 24) == b1) atomicAdd(&h[(bits >> 12) & 0xFFFu], 1u); }
        else { if ((bits >> 12) == ((b1 << 12) | b2)) atomicAdd(&h[bits & 0xFFFu], 1u); }
    }
    __syncthreads();
    for (int i = threadIdx.x; i < 4096; i += 256)
        if (h[i]) atomicAdd(&H[i], h[i]);
}

__global__ __launch_bounds__(1024)
void scan_kernel(const unsigned* __restrict__ hist, int* __restrict__ sel, int pass)
{
    __shared__ unsigned ps[1024];
    int n = blockIdx.x;
    const unsigned* H = hist + n * 4096;
    int* SL = sel + n * 8;
    int tid = threadIdx.x;
    unsigned s = 0;
    if (pass == 0) s = (tid < 256) ? H[tid] : 0u;
    else { for (int b = 0; b < 4; ++b) s += H[tid * 4 + b]; }
    ps[tid] = s;
    __syncthreads();
    if (tid == 0) {
        unsigned base = 0;
        if (pass == 1) base = (unsigned)SL[1];
        else if (pass == 2) base = (unsigned)SL[3];
        unsigned cum = base, prev = 0;
        int fb = -1;
        for (int t = 1023; t >= 0; --t) {
            if (cum + ps[t] >= (unsigned)KTOP) {
                if (pass == 0) { fb = t; prev = cum; }
                else {
                    for (int b = t * 4 + 3; b >= t * 4; --b) {
                        unsigned c = H[b];
                        if (cum + c >= (unsigned)KTOP) { fb = b; prev = cum; break; }
                        cum += c;
                    }
                }
                break;
            }
            cum += ps[t];
        }
        if (pass == 0) { SL[0] = fb; SL[1] = (int)prev; }
        else if (pass == 1) { SL[2] = fb; SL[3] = (int)prev; }
        else {
            unsigned T = (((unsigned)SL[0]) << 24) | (((unsigned)SL[2]) << 12) | (unsigned)fb;
            SL[4] = (int)T; SL[5] = KTOP - (int)prev; SL[6] = (int)prev;
        }
    }
}

__global__ __launch_bounds__(256)
void compact_kernel(const float* __restrict__ scores, int nElems, const int* __restrict__ sel,
                    int* __restrict__ candIdx, float* __restrict__ candScore,
                    unsigned* __restrict__ eqList, int* __restrict__ counters, int lvl)
{
    int n = blockIdx.y;
    const float* S = scores + (size_t)n * nElems;
    unsigned T = (unsigned)sel[n * 8 + 4];
    int* cnt = counters + n * 2;
    int stride = gridDim.x * 256;
    for (int i = blockIdx.x * 256 + threadIdx.x; i < nElems; i += stride) {
        unsigned bits = __float_as_uint(S[i]);
        if (bits > T) {
            int s = atomicAdd(&cnt[0], 1);
            if (s < KTOP) {
                candIdx[n * 5000 + lvl * 1000 + s] = i;
                candScore[n * 5000 + lvl * 1000 + s] = S[i];
            }
        } else if (bits == T) {
            int e = atomicAdd(&cnt[1], 1);
            if (e < 4096) eqList[n * 4096 + e] = (unsigned)i;
        }
    }
}

template<typename T>
__device__ inline void bitonicSort(T* a, int N, bool desc)
{
    for (int k = 2; k <= N; k <<= 1)
        for (int j = k >> 1; j >= 1; j >>= 1) {
            for (int i = threadIdx.x; i < N; i += blockDim.x) {
                int l = i ^ j;
                if (l > i) {
                    T x = a[i], y = a[l];
                    bool up = ((i & k) == 0);
                    bool sw = desc ? (up ? (x < y) : (x > y)) : (up ? (x > y) : (x < y));
                    if (sw) { a[i] = y; a[l] = x; }
                }
            }
            __syncthreads();
        }
}

__global__ __launch_bounds__(256)
void eqfinish_kernel(const unsigned* __restrict__ eqList, const int* __restrict__ sel,
                     const int* __restrict__ counters, int* __restrict__ candIdx,
                     float* __restrict__ candScore, int lvl)
{
    __shared__ unsigned L[4096];
    int n = blockIdx.x;
    int e = counters[n * 2 + 1]; if (e > 4096) e = 4096;
    int needEq = sel[n * 8 + 5];
    int base = sel[n * 8 + 6];
    unsigned T = (unsigned)sel[n * 8 + 4];
    for (int i = threadIdx.x; i < 4096; i += 256) L[i] = (i < e) ? eqList[n * 4096 + i] : 0xFFFFFFFFu;
    __syncthreads();
    bitonicSort(L, 4096, false);
    for (int t = threadIdx.x; t < needEq; t += 256) {
        int s = base + t;
        if (s < KTOP) {
            candIdx[n * 5000 + lvl * 1000 + s] = (int)L[t];
            candScore[n * 5000 + lvl * 1000 + s] = __uint_as_float(T);
        }
    }
}

__global__ __launch_bounds__(256)
void lvlsort_kernel(int* __restrict__ candIdx, float* __restrict__ candScore, int lvl)
{
    __shared__ unsigned long long K[1024];
    int n = blockIdx.x;
    int* CI = candIdx + n * 5000 + lvl * 1000;
    float* CS = candScore + n * 5000 + lvl * 1000;
    for (int i = threadIdx.x; i < 1024; i += blockDim.x)
        K[i] = (i < KTOP)
             ? ((((unsigned long long)(unsigned)CI[i]) << 32) | __float_as_uint(CS[i]))
             : 0xFFFFFFFFFFFFFFFFULL;
    __syncthreads();
    bitonicSort(K, 1024, false);
    for (int i = threadIdx.x; i < KTOP; i += blockDim.x) {
        CI[i] = (int)(K[i] >> 32);
        CS[i] = __uint_as_float((unsigned)(K[i] & 0xFFFFFFFFu));
    }
}

__global__ __launch_bounds__(256)
void decode_kernel(const int* __restrict__ candIdx, const float* __restrict__ candScore,
                   const float* __restrict__ deltas, float* __restrict__ candBox,
                   float* __restrict__ candZ, int* __restrict__ candCls,
                   int HW, int W, int lvl, float stride)
{
    int t = blockIdx.x * 256 + threadIdx.x;
    if (t >= 2 * KTOP) return;
    int n = t / KTOP, s = t % KTOP;
    int g = n * 5000 + lvl * 1000 + s;
    int idx = candIdx[g];
    float raw = candScore[g];
    int pos = idx / NCLS, cls = idx % NCLS;
    int hh = pos / W, ww = pos % W;
    float cxa0 = ((float)ww + 0.5f) * stride;
    float cya0 = ((float)hh + 0.5f) * stride;
    float half = 2.f * stride;
    float a0 = cxa0 - half, a1 = cya0 - half, a2 = cxa0 + half, a3 = cya0 + half;
    float wa = a2 - a0, ha = a3 - a1;
    float cxa = a0 + 0.5f * wa, cya = a1 + 0.5f * ha;
    const float* D = deltas + (size_t)n * 4 * HW;
    float dx = D[pos], dy = D[HW + pos], dw = D[2 * HW + pos], dh = D[3 * HW + pos];
    dw = fminf(dw, SCALE_CLAMP); dh = fminf(dh, SCALE_CLAMP);
    float cx = dx * wa + cxa, cy = dy * ha + cya;
    float w2 = expf(dw) * wa, h2 = expf(dh) * ha;
    float x1 = fminf(fmaxf(cx - 0.5f * w2, 0.f), IMGW);
    float y1 = fminf(fmaxf(cy - 0.5f * h2, 0.f), IMGH);
    float x2 = fminf(fmaxf(cx + 0.5f * w2, 0.f), IMGW);
    float y2 = fminf(fmaxf(cy + 0.5f * h2, 0.f), IMGH);
    candBox[g * 4 + 0] = x1; candBox[g * 4 + 1] = y1;
    candBox[g * 4 + 2] = x2; candBox[g * 4 + 3] = y2;
    candZ[g] = (raw > SCORE_T) ? raw : 0.f;
    candCls[g] = cls;
}

__global__ __launch_bounds__(1024)
void gsort_kernel(const float* __restrict__ candZ, const float* __restrict__ candBox,
                  const int* __restrict__ candCls, float* __restrict__ sBox,
                  float* __restrict__ sScore, float* __restrict__ sCls,
                  float* __restrict__ sOffB, float* __restrict__ sArea)
{
    __shared__ unsigned long long K[8192];
    int n = blockIdx.x;
    for (int i = threadIdx.x; i < 8192; i += 1024)
        K[i] = (i < 5000)
             ? ((((unsigned long long)__float_as_uint(candZ[n * 5000 + i])) << 16)
                | (unsigned long long)(65535 - i))
             : 0ULL;
    __syncthreads();
    bitonicSort(K, 8192, true);
    for (int r = threadIdx.x; r < 5000; r += 1024) {
        unsigned long long k = K[r];
        int g = 65535 - (int)(k & 0xFFFFULL);
        float s = __uint_as_float((unsigned)((k >> 16) & 0xFFFFFFFFULL));
        int cls = candCls[n * 5000 + g];
        float b0 = candBox[(n * 5000 + g) * 4 + 0];
        float b1 = candBox[(n * 5000 + g) * 4 + 1];
        float b2 = candBox[(n * 5000 + g) * 4 + 2];
        float b3 = candBox[(n * 5000 + g) * 4 + 3];
        size_t o = (size_t)n * 5000 + r;
        sBox[o * 4 + 0] = b0; sBox[o * 4 + 1] = b1; sBox[o * 4 + 2] = b2; sBox[o * 4 + 3] = b3;
        sScore[o] = s;
        sCls[o] = (float)cls;
        float off = (float)cls * 2000.0f;
        float o0 = b0 + off, o1 = b1 + off, o2 = b2 + off, o3 = b3 + off;
        sOffB[o * 4 + 0] = o0; sOffB[o * 4 + 1] = o1; sOffB[o * 4 + 2] = o2; sOffB[o * 4 + 3] = o3;
        sArea[o] = (o2 - o0) * (o3 - o1);
    }
}

__global__ __launch_bounds__(1024)
void nms_kernel(const float* __restrict__ sBox, const float* __restrict__ sScore,
                const float* __restrict__ sCls, const float* __restrict__ sOffB,
                const float* __restrict__ sArea, float* __restrict__ out)
{
    __shared__ unsigned char keep[5000];
    __shared__ int alive[100], dead[100], counts[2];
    int n = blockIdx.x;
    int tid = threadIdx.x;
    const float* B = sOffB + (size_t)n * 5000 * 4;
    const float* A = sArea + (size_t)n * 5000;
    const float* S = sScore + (size_t)n * 5000;
    for (int i = tid; i < 5000; i += 1024) keep[i] = 1;
    __syncthreads();
    for (int i = 0; i < 5000; ++i) {
        if (!keep[i]) continue;
        float si = S[i];
        if (!(si > 0.f)) continue;
        float bx0 = B[i * 4], bx1 = B[i * 4 + 1], bx2 = B[i * 4 + 2], bx3 = B[i * 4 + 3];
        float ai = A[i];
        for (int j = i + 1 + tid; j < 5000; j += 1024) {
            float xx1 = fmaxf(bx0, B[j * 4]);
            float yy1 = fmaxf(bx1, B[j * 4 + 1]);
            float xx2 = fminf(bx2, B[j * 4 + 2]);
            float yy2 = fminf(bx3, B[j * 4 + 3]);
            float iw = fmaxf(xx2 - xx1, 0.f), ih = fmaxf(yy2 - yy1, 0.f);
            float inter = iw * ih;
            float iou = inter / (ai + A[j] - inter + 1e-9f);
            if (iou > NMS_T) keep[j] = 0;
        }
        __syncthreads();
    }
    if (tid == 0) {
        int na = 0, nd = 0;
        for (int i = 0; i < 5000 && (na < 100 || nd < 100); ++i) {
            float m = keep[i] ? S[i] : 0.f;
            if (m > 0.f) { if (na < 100) alive[na++] = i; }
            else { if (nd < 100) dead[nd++] = i; }
        }
        counts[0] = na; counts[1] = nd;
    }
    __syncthreads();
    int na = counts[0];
    for (int r = tid; r < 100; r += 1024) {
        int p; float sc;
        if (r < na) { p = alive[r]; sc = S[p]; }
        else { p = dead[r - na]; sc = 0.f; }
        const float* bb = sBox + (((size_t)n * 5000) + p) * 4;
        out[(n * 100 + r) * 4 + 0] = bb[0];
        out[(n * 100 + r) * 4 + 1] = bb[1];
        out[(n * 100 + r) * 4 + 2] = bb[2];
        out[(n * 100 + r) * 4 + 3] = bb[3];
        out[800 + n * 100 + r] = sc;
        out[1000 + n * 100 + r] = sCls[(size_t)n * 5000 + p];
    }
}

// ----------------------------------------------------------------------------
extern "C" void kernel_launch(void* const* d_in, const int* in_sizes, int n_in,
                              void* d_out, int out_size, void* d_ws, size_t ws_size,
                              hipStream_t stream)
{
    const float* feat[5] = { (const float*)d_in[0], (const float*)d_in[1],
                             (const float*)d_in[2], (const float*)d_in[3],
                             (const float*)d_in[4] };
    const float* cls_w   = (const float*)d_in[5];
    const float* cls_b   = (const float*)d_in[6];
    const float* box_w   = (const float*)d_in[7];
    const float* box_b   = (const float*)d_in[8];
    const float* score_w = (const float*)d_in[9];
    const float* score_b = (const float*)d_in[10];
    const float* pred_w  = (const float*)d_in[11];
    const float* pred_b  = (const float*)d_in[12];
    const float* ctr_w   = (const float*)d_in[13];
    const float* ctr_b   = (const float*)d_in[14];

    char* ws = (char*)d_ws;
    size_t off = 0;
    auto alloc = [&](size_t nbytes) -> void* {
        void* p = ws + off;
        off += (nbytes + 255) & ~(size_t)255;
        return p;
    };
    const int HWmax = 128 * 168;
    float* ping   = (float*)alloc(sizeof(float) * 2 * 256 * (size_t)HWmax);
    float* pong   = (float*)alloc(sizeof(float) * 2 * 256 * (size_t)HWmax);
    float* lg81   = (float*)alloc(sizeof(float) * 2 * 81 * (size_t)HWmax);
    float* deltas = (float*)alloc(sizeof(float) * 2 * 4 * (size_t)HWmax);
    float* scores = (float*)alloc(sizeof(float) * 2 * (size_t)HWmax * 80);
    float* packw  = (float*)alloc(sizeof(float) * 81 * 2304);
    float* packb  = (float*)alloc(sizeof(float) * 256);
    unsigned* hist = (unsigned*)alloc(sizeof(unsigned) * 2 * 4096);
    int* sel       = (int*)alloc(sizeof(int) * 2 * 8);
    int* counters  = (int*)alloc(sizeof(int) * 2 * 2);
    unsigned* eqList = (unsigned*)alloc(sizeof(unsigned) * 2 * 4096);
    int* candIdx     = (int*)alloc(sizeof(int) * 2 * 5000);
    float* candScore = (float*)alloc(sizeof(float) * 2 * 5000);
    float* candZ     = (float*)alloc(sizeof(float) * 2 * 5000);
    float* candBox   = (float*)alloc(sizeof(float) * 2 * 5000 * 4);
    int* candCls     = (int*)alloc(sizeof(int) * 2 * 5000);
    float* sBox   = (float*)alloc(sizeof(float) * 2 * 5000 * 4);
    float* sScore = (float*)alloc(sizeof(float) * 2 * 5000);
    float* sCls   = (float*)alloc(sizeof(float) * 2 * 5000);
    float* sOffB  = (float*)alloc(sizeof(float) * 2 * 5000 * 4);
    float* sArea  = (float*)alloc(sizeof(float) * 2 * 5000);

    pack_kernel<<<(81 * 2304 + 255) / 256, 256, 0, stream>>>(score_w, score_b, ctr_w, ctr_b, packw, packb);

    const int   LH[5] = { 128, 64, 32, 16, 8 };
    const int   LW[5] = { 168, 84, 42, 21, 11 };
    const float LS[5] = { 8.f, 16.f, 32.f, 64.f, 128.f };

    for (int lvl = 0; lvl < 5; ++lvl) {
        int H = LH[lvl], W = LW[lvl], HW = H * W;
        int tilesX = (W + 15) / 16, tilesY = (H + 7) / 8;
        dim3 gT(tilesX * tilesY, 2, 4);
        dim3 gH(tilesX * tilesY, 2, 2);
        dim3 gP(tilesX * tilesY, 2, 1);
        const size_t WS = 589824;  // 256*256*9

        conv3x3<1><<<gT, 256, 0, stream>>>(feat[lvl], cls_w + 0 * WS, cls_b + 0,   ping, H, W, 256, tilesX);
        conv3x3<1><<<gT, 256, 0, stream>>>(ping,      cls_w + 1 * WS, cls_b + 256, pong, H, W, 256, tilesX);
        conv3x3<1><<<gT, 256, 0, stream>>>(pong,      cls_w + 2 * WS, cls_b + 512, ping, H, W, 256, tilesX);
        conv3x3<1><<<gT, 256, 0, stream>>>(ping,      cls_w + 3 * WS, cls_b + 768, pong, H, W, 256, tilesX);
        conv3x3<0><<<gH, 256, 0, stream>>>(pong, packw, packb, lg81, H, W, 81, tilesX);

        conv3x3<1><<<gT, 256, 0, stream>>>(feat[lvl], box_w + 0 * WS, box_b + 0,   ping, H, W, 256, tilesX);
        conv3x3<1><<<gT, 256, 0, stream>>>(ping,      box_w + 1 * WS, box_b + 256, pong, H, W, 256, tilesX);
        conv3x3<1><<<gT, 256, 0, stream>>>(pong,      box_w + 2 * WS, box_b + 512, ping, H, W, 256, tilesX);
        conv3x3<1><<<gT, 256, 0, stream>>>(ping,      box_w + 3 * WS, box_b + 768, pong, H, W, 256, tilesX);
        conv3x3<0><<<gP, 256, 0, stream>>>(pong, pred_w, pred_b, deltas, H, W, 4, tilesX);

        dim3 gS((HW + 63) / 64, 2);
        score_kernel<<<gS, 256, 0, stream>>>(lg81, scores, HW);
        int nel = HW * 80;
        int hb = (nel + 255) / 256; if (hb > 512) hb = 512;
        dim3 gHist(hb, 2);
        hipMemsetAsync(hist, 0, 2 * 4096 * sizeof(unsigned), stream);
        hist_kernel<<<gHist, 256, 0, stream>>>(scores, hist, sel, nel, 0);
        scan_kernel<<<2, 1024, 0, stream>>>(hist, sel, 0);
        hipMemsetAsync(hist, 0, 2 * 4096 * sizeof(unsigned), stream);
        hist_kernel<<<gHist, 256, 0, stream>>>(scores, hist, sel, nel, 1);
        scan_kernel<<<2, 1024, 0, stream>>>(hist, sel, 1);
        hipMemsetAsync(hist, 0, 2 * 4096 * sizeof(unsigned), stream);
        hist_kernel<<<gHist, 256, 0, stream>>>(scores, hist, sel, nel, 2);
        scan_kernel<<<2, 1024, 0, stream>>>(hist, sel, 2);
        hipMemsetAsync(counters, 0, 2 * 2 * sizeof(int), stream);
        compact_kernel<<<gHist, 256, 0, stream>>>(scores, nel, sel, candIdx, candScore, eqList, counters, lvl);
        eqfinish_kernel<<<2, 256, 0, stream>>>(eqList, sel, counters, candIdx, candScore, lvl);
        lvlsort_kernel<<<2, 256, 0, stream>>>(candIdx, candScore, lvl);
        decode_kernel<<<(2 * KTOP + 255) / 256, 256, 0, stream>>>(candIdx, candScore, deltas,
                                                                  candBox, candZ, candCls,
                                                                  HW, W, lvl, LS[lvl]);
    }
    gsort_kernel<<<2, 1024, 0, stream>>>(candZ, candBox, candCls, sBox, sScore, sCls, sOffB, sArea);
    nms_kernel<<<2, 1024, 0, stream>>>(sBox, sScore, sCls, sOffB, sArea, (float*)d_out);
}

// Round 2
// 13262.445 us; speedup vs baseline: 2.4868x; 2.4868x over previous
//
#include <hip/hip_runtime.h>
#include <math.h>

#define NCLS 80
#define KTOP 1000
#define SCORE_T 0.05f
#define NMS_T 0.6f
#define SCALE_CLAMP 4.135166556742356f
#define IMGW 1344.0f
#define IMGH 1024.0f

// ----------------------------------------------------------------------------
// 3x3 same-pad conv, Cin=256, dual-tower (z selects tower A or B).
// Block: 256 thr -> 64 couts x (8x16) tile. Each thread: 4 couts x (2x4) pos.
// ci-block=8, reg-staged async double buffer (issue loads early, ds_write late).
// Numerically identical to round-1 conv3x3 (same fmaf order per output).
// ----------------------------------------------------------------------------
template<int RELU>
__global__ __launch_bounds__(256, 2)
void conv_dual(const float* __restrict__ inA, const float* __restrict__ inB,
               const float* __restrict__ wA, const float* __restrict__ wB,
               const float* __restrict__ bA, const float* __restrict__ bB,
               float* __restrict__ outA, float* __restrict__ outB,
               int H, int W, int CoutA, int CoutB, int zA, int tilesX)
{
    __shared__ float sIn[8][10][20];   // padded cols (18 valid) -> aligned b128
    __shared__ float sWt[64][74];      // 72 valid, pad 74 -> conflict-free
    const int tid  = threadIdx.x;
    const int tile = blockIdx.x;
    const int n    = blockIdx.y;
    const int z    = blockIdx.z;
    const bool isA = (z < zA);
    const float* in   = isA ? inA : inB;
    const float* wt   = isA ? wA : wB;
    const float* bias = isA ? bA : bB;
    float* out        = isA ? outA : outB;
    const int Cout    = isA ? CoutA : CoutB;
    const int cout0   = (isA ? z : z - zA) * 64;

    const int ty = tile / tilesX, tx = tile % tilesX;
    const int h0 = ty * 8, w0 = tx * 16;
    const int HW = H * W;
    const float* inN = in + (size_t)n * 256 * HW;
    const int cell = tid & 15, cg = tid >> 4;
    const int pr = (cell >> 2) << 1;   // 0,2,4,6
    const int pc = (cell & 3) << 2;    // 0,4,8,12
    // staging mappings
    const int q = tid & 3, pp0 = tid >> 2;        // input: (ci,row) pair + col group
    const int wcout = tid & 63, wpart = tid >> 6; // weights: cout + 18-float part
    const int gcout_st = cout0 + wcout;
    const float* wbase = wt + (size_t)gcout_st * 2304 + wpart * 18;

    float acc[4][8];
#pragma unroll
    for (int a = 0; a < 4; ++a)
#pragma unroll
        for (int b = 0; b < 8; ++b) acc[a][b] = 0.f;

    float rIn[10];
    float rW[18];

    auto issue = [&](int ci0) {
#pragma unroll
        for (int it = 0; it < 2; ++it) {
            int p = pp0 + it * 64;
            if (p < 80) {
                int ci = p / 10, row = p - ci * 10;
                int gh = h0 + row - 1;
                const float* src = inN + (size_t)(ci0 + ci) * HW;
#pragma unroll
                for (int j = 0; j < 5; ++j) {
                    int col = q * 5 + j, gw = w0 + col - 1;
                    float v = 0.f;
                    if (col < 18 && (unsigned)gh < (unsigned)H && (unsigned)gw < (unsigned)W)
                        v = src[(long)gh * W + gw];
                    rIn[it * 5 + j] = v;
                }
            }
        }
        const float* wp = wbase + ci0 * 9;
#pragma unroll
        for (int j = 0; j < 18; ++j)
            rW[j] = (gcout_st < Cout) ? wp[j] : 0.f;
    };
    auto commit = [&]() {
#pragma unroll
        for (int it = 0; it < 2; ++it) {
            int p = pp0 + it * 64;
            if (p < 80) {
                int ci = p / 10, row = p - ci * 10;
#pragma unroll
                for (int j = 0; j < 5; ++j) {
                    int col = q * 5 + j;
                    if (col < 18) sIn[ci][row][col] = rIn[it * 5 + j];
                }
            }
        }
#pragma unroll
        for (int j = 0; j < 18; ++j) sWt[wcout][wpart * 18 + j] = rW[j];
    };

    issue(0);
    commit();
    __syncthreads();

    for (int rstep = 0; rstep < 32; ++rstep) {
        if (rstep < 31) issue((rstep + 1) * 8);
#pragma unroll 2
        for (int ci = 0; ci < 8; ++ci) {
            float x[4][6];
#pragma unroll
            for (int r = 0; r < 4; ++r)
#pragma unroll
                for (int c2 = 0; c2 < 6; ++c2) x[r][c2] = sIn[ci][pr + r][pc + c2];
#pragma unroll
            for (int cc = 0; cc < 4; ++cc) {
                float wv[9];
#pragma unroll
                for (int k = 0; k < 9; ++k) wv[k] = sWt[cg * 4 + cc][ci * 9 + k];
#pragma unroll
                for (int py = 0; py < 2; ++py)
#pragma unroll
                    for (int px = 0; px < 4; ++px) {
                        float s = acc[cc][py * 4 + px];
#pragma unroll
                        for (int dy = 0; dy < 3; ++dy)
#pragma unroll
                            for (int dx = 0; dx < 3; ++dx)
                                s = fmaf(wv[dy * 3 + dx], x[py + dy][px + dx], s);
                        acc[cc][py * 4 + px] = s;
                    }
            }
        }
        __syncthreads();
        if (rstep < 31) { commit(); __syncthreads(); }
    }

#pragma unroll
    for (int cc = 0; cc < 4; ++cc) {
        int gc = cout0 + cg * 4 + cc;
        if (gc >= Cout) continue;
        float b = bias[gc];
        float* outc = out + ((size_t)n * Cout + gc) * HW;
#pragma unroll
        for (int py = 0; py < 2; ++py) {
            int gh = h0 + pr + py;
            if (gh >= H) continue;
#pragma unroll
            for (int px = 0; px < 4; ++px) {
                int gw = w0 + pc + px;
                if (gw >= W) continue;
                float v = acc[cc][py * 4 + px] + b;
                if (RELU) v = fmaxf(v, 0.f);
                outc[gh * W + gw] = v;
            }
        }
    }
}

// ----------------------------------------------------------------------------
__global__ void pack_kernel(const float* __restrict__ sw, const float* __restrict__ sb,
                            const float* __restrict__ cw, const float* __restrict__ cb,
                            float* __restrict__ pw, float* __restrict__ pb)
{
    int i = blockIdx.x * 256 + threadIdx.x;
    const int tot = 81 * 2304;
    if (i < tot) pw[i] = (i < 80 * 2304) ? sw[i] : cw[i - 80 * 2304];
    if (i < 81)  pb[i] = (i < 80) ? sb[i] : cb[i - 80];
}

// ----------------------------------------------------------------------------
__global__ __launch_bounds__(256)
void score_kernel(const float* __restrict__ lg, float* __restrict__ scores, int HW)
{
    __shared__ float tile[64 * 81];
    __shared__ float sctr[64];
    int n = blockIdx.y;
    int pos0 = blockIdx.x * 64;
    int tid = threadIdx.x;
    const float* L = lg + (size_t)n * 81 * HW;
    if (tid < 64) {
        int p = pos0 + tid;
        float c = (p < HW) ? L[(size_t)80 * HW + p] : 0.f;
        sctr[tid] = 1.f / (1.f + expf(-c));
    }
    __syncthreads();
    for (int e = tid; e < 64 * NCLS; e += 256) {
        int c = e >> 6;
        int p = e & 63;
        int gp = pos0 + p;
        float l = (gp < HW) ? L[(size_t)c * HW + gp] : 0.f;
        float sl = 1.f / (1.f + expf(-l));
        tile[p * 81 + c] = sqrtf(sl * sctr[p]);
    }
    __syncthreads();
    float* dst = scores + (size_t)n * HW * NCLS + (size_t)pos0 * NCLS;
    int valid = HW - pos0; if (valid > 64) valid = 64;
    int lim = valid * NCLS;
    for (int e = tid; e < lim; e += 256) dst[e] = tile[(e / 80) * 81 + e % 80];
}

// ----------------------------------------------------------------------------
__global__ __launch_bounds__(256)
void hist_kernel(const float* __restrict__ scores, unsigned* __restrict__ hist,
                 const int* __restrict__ sel, int nElems, int pass)
{
    __shared__ unsigned h[4096];
    int n = blockIdx.y;
    const float* S = scores + (size_t)n * nElems;
    unsigned* H = hist + n * 4096;
    const int* SL = sel + n * 8;
    for (int i = threadIdx.x; i < 4096; i += 256) h[i] = 0;
    __syncthreads();
    unsigned b1 = 0, b2 = 0;
    if (pass >= 1) b1 = (unsigned)SL[0];
    if (pass == 2) b2 = (unsigned)SL[2];
    int stride = gridDim.x * 256;
    for (int i = blockIdx.x * 256 + threadIdx.x; i < nElems; i += stride) {
        unsigned bits = __float_as_uint(S[i]);
        if (pass == 0) atomicAdd(&h[bits >> 24], 1u);
        else if (pass == 1) { if ((bits >> 24) == b1) atomicAdd(&h[(bits >> 12) & 0xFFFu], 1u); }
        else { if ((bits >> 12) == ((b1 << 12) | b2)) atomicAdd(&h[bits & 0xFFFu], 1u); }
    }
    __syncthreads();
    for (int i = threadIdx.x; i < 4096; i += 256)
        if (h[i]) atomicAdd(&H[i], h[i]);
}

__global__ __launch_bounds__(1024)
void scan_kernel(const unsigned* __restrict__ hist, int* __restrict__ sel, int pass)
{
    __shared__ unsigned ps[1024];
    int n = blockIdx.x;
    const unsigned* H = hist + n * 4096;
    int* SL = sel + n * 8;
    int tid = threadIdx.x;
    unsigned s = 0;
    if (pass == 0) s = (tid < 256) ? H[tid] : 0u;
    else { for (int b = 0; b < 4; ++b) s += H[tid * 4 + b]; }
    ps[tid] = s;
    __syncthreads();
    if (tid == 0) {
        unsigned base = 0;
        if (pass == 1) base = (unsigned)SL[1];
        else if (pass == 2) base = (unsigned)SL[3];
        unsigned cum = base, prev = 0;
        int fb = -1;
        for (int t = 1023; t >= 0; --t) {
            if (cum + ps[t] >= (unsigned)KTOP) {
                if (pass == 0) { fb = t; prev = cum; }
                else {
                    for (int b = t * 4 + 3; b >= t * 4; --b) {
                        unsigned c = H[b];
                        if (cum + c >= (unsigned)KTOP) { fb = b; prev = cum; break; }
                        cum += c;
                    }
                }
                break;
            }
            cum += ps[t];
        }
        if (pass == 0) { SL[0] = fb; SL[1] = (int)prev; }
        else if (pass == 1) { SL[2] = fb; SL[3] = (int)prev; }
        else {
            unsigned T = (((unsigned)SL[0]) << 24) | (((unsigned)SL[2]) << 12) | (unsigned)fb;
            SL[4] = (int)T; SL[5] = KTOP - (int)prev; SL[6] = (int)prev;
        }
    }
}

__global__ __launch_bounds__(256)
void compact_kernel(const float* __restrict__ scores, int nElems, const int* __restrict__ sel,
                    int* __restrict__ candIdx, float* __restrict__ candScore,
                    unsigned* __restrict__ eqList, int* __restrict__ counters, int lvl)
{
    int n = blockIdx.y;
    const float* S = scores + (size_t)n * nElems;
    unsigned T = (unsigned)sel[n * 8 + 4];
    int* cnt = counters + n * 2;
    int stride = gridDim.x * 256;
    for (int i = blockIdx.x * 256 + threadIdx.x; i < nElems; i += stride) {
        unsigned bits = __float_as_uint(S[i]);
        if (bits > T) {
            int s = atomicAdd(&cnt[0], 1);
            if (s < KTOP) {
                candIdx[n * 5000 + lvl * 1000 + s] = i;
                candScore[n * 5000 + lvl * 1000 + s] = S[i];
            }
        } else if (bits == T) {
            int e = atomicAdd(&cnt[1], 1);
            if (e < 4096) eqList[n * 4096 + e] = (unsigned)i;
        }
    }
}

template<typename T>
__device__ inline void bitonicSort(T* a, int N, bool desc)
{
    for (int k = 2; k <= N; k <<= 1)
        for (int j = k >> 1; j >= 1; j >>= 1) {
            for (int i = threadIdx.x; i < N; i += blockDim.x) {
                int l = i ^ j;
                if (l > i) {
                    T x = a[i], y = a[l];
                    bool up = ((i & k) == 0);
                    bool sw = desc ? (up ? (x < y) : (x > y)) : (up ? (x > y) : (x < y));
                    if (sw) { a[i] = y; a[l] = x; }
                }
            }
            __syncthreads();
        }
}

__global__ __launch_bounds__(256)
void eqfinish_kernel(const unsigned* __restrict__ eqList, const int* __restrict__ sel,
                     const int* __restrict__ counters, int* __restrict__ candIdx,
                     float* __restrict__ candScore, int lvl)
{
    __shared__ unsigned L[4096];
    int n = blockIdx.x;
    int e = counters[n * 2 + 1]; if (e > 4096) e = 4096;
    int needEq = sel[n * 8 + 5];
    int base = sel[n * 8 + 6];
    unsigned T = (unsigned)sel[n * 8 + 4];
    for (int i = threadIdx.x; i < 4096; i += 256) L[i] = (i < e) ? eqList[n * 4096 + i] : 0xFFFFFFFFu;
    __syncthreads();
    bitonicSort(L, 4096, false);
    for (int t = threadIdx.x; t < needEq; t += 256) {
        int s = base + t;
        if (s < KTOP) {
            candIdx[n * 5000 + lvl * 1000 + s] = (int)L[t];
            candScore[n * 5000 + lvl * 1000 + s] = __uint_as_float(T);
        }
    }
}

__global__ __launch_bounds__(256)
void lvlsort_kernel(int* __restrict__ candIdx, float* __restrict__ candScore, int lvl)
{
    __shared__ unsigned long long K[1024];
    int n = blockIdx.x;
    int* CI = candIdx + n * 5000 + lvl * 1000;
    float* CS = candScore + n * 5000 + lvl * 1000;
    for (int i = threadIdx.x; i < 1024; i += blockDim.x)
        K[i] = (i < KTOP)
             ? ((((unsigned long long)(unsigned)CI[i]) << 32) | __float_as_uint(CS[i]))
             : 0xFFFFFFFFFFFFFFFFULL;
    __syncthreads();
    bitonicSort(K, 1024, false);
    for (int i = threadIdx.x; i < KTOP; i += blockDim.x) {
        CI[i] = (int)(K[i] >> 32);
        CS[i] = __uint_as_float((unsigned)(K[i] & 0xFFFFFFFFu));
    }
}

__global__ __launch_bounds__(256)
void decode_kernel(const int* __restrict__ candIdx, const float* __restrict__ candScore,
                   const float* __restrict__ deltas, float* __restrict__ candBox,
                   float* __restrict__ candZ, int* __restrict__ candCls,
                   int HW, int W, int lvl, float stride)
{
    int t = blockIdx.x * 256 + threadIdx.x;
    if (t >= 2 * KTOP) return;
    int n = t / KTOP, s = t % KTOP;
    int g = n * 5000 + lvl * 1000 + s;
    int idx = candIdx[g];
    float raw = candScore[g];
    int pos = idx / NCLS, cls = idx % NCLS;
    int hh = pos / W, ww = pos % W;
    float cxa0 = ((float)ww + 0.5f) * stride;
    float cya0 = ((float)hh + 0.5f) * stride;
    float half = 2.f * stride;
    float a0 = cxa0 - half, a1 = cya0 - half, a2 = cxa0 + half, a3 = cya0 + half;
    float wa = a2 - a0, ha = a3 - a1;
    float cxa = a0 + 0.5f * wa, cya = a1 + 0.5f * ha;
    const float* D = deltas + (size_t)n * 4 * HW;
    float dx = D[pos], dy = D[HW + pos], dw = D[2 * HW + pos], dh = D[3 * HW + pos];
    dw = fminf(dw, SCALE_CLAMP); dh = fminf(dh, SCALE_CLAMP);
    float cx = dx * wa + cxa, cy = dy * ha + cya;
    float w2 = expf(dw) * wa, h2 = expf(dh) * ha;
    float x1 = fminf(fmaxf(cx - 0.5f * w2, 0.f), IMGW);
    float y1 = fminf(fmaxf(cy - 0.5f * h2, 0.f), IMGH);
    float x2 = fminf(fmaxf(cx + 0.5f * w2, 0.f), IMGW);
    float y2 = fminf(fmaxf(cy + 0.5f * h2, 0.f), IMGH);
    candBox[g * 4 + 0] = x1; candBox[g * 4 + 1] = y1;
    candBox[g * 4 + 2] = x2; candBox[g * 4 + 3] = y2;
    candZ[g] = (raw > SCORE_T) ? raw : 0.f;
    candCls[g] = cls;
}

__global__ __launch_bounds__(1024)
void gsort_kernel(const float* __restrict__ candZ, const float* __restrict__ candBox,
                  const int* __restrict__ candCls, float* __restrict__ sBox,
                  float* __restrict__ sScore, float* __restrict__ sCls,
                  float* __restrict__ sOffB, float* __restrict__ sArea)
{
    __shared__ unsigned long long K[8192];
    int n = blockIdx.x;
    for (int i = threadIdx.x; i < 8192; i += 1024)
        K[i] = (i < 5000)
             ? ((((unsigned long long)__float_as_uint(candZ[n * 5000 + i])) << 16)
                | (unsigned long long)(65535 - i))
             : 0ULL;
    __syncthreads();
    bitonicSort(K, 8192, true);
    for (int r = threadIdx.x; r < 5000; r += 1024) {
        unsigned long long k = K[r];
        int g = 65535 - (int)(k & 0xFFFFULL);
        float s = __uint_as_float((unsigned)((k >> 16) & 0xFFFFFFFFULL));
        int cls = candCls[n * 5000 + g];
        float b0 = candBox[(n * 5000 + g) * 4 + 0];
        float b1 = candBox[(n * 5000 + g) * 4 + 1];
        float b2 = candBox[(n * 5000 + g) * 4 + 2];
        float b3 = candBox[(n * 5000 + g) * 4 + 3];
        size_t o = (size_t)n * 5000 + r;
        sBox[o * 4 + 0] = b0; sBox[o * 4 + 1] = b1; sBox[o * 4 + 2] = b2; sBox[o * 4 + 3] = b3;
        sScore[o] = s;
        sCls[o] = (float)cls;
        float off = (float)cls * 2000.0f;
        float o0 = b0 + off, o1 = b1 + off, o2 = b2 + off, o3 = b3 + off;
        sOffB[o * 4 + 0] = o0; sOffB[o * 4 + 1] = o1; sOffB[o * 4 + 2] = o2; sOffB[o * 4 + 3] = o3;
        sArea[o] = (o2 - o0) * (o3 - o1);
    }
}

// ----------------------------------------------------------------------------
// NMS stage 1: parallel IoU bitmasks. masks[(n*5000+i)*79 + jw] bit u =
// (IoU(i, jw*64+u) > NMS_T), exact same float expression as reference.
// ----------------------------------------------------------------------------
__global__ __launch_bounds__(64)
void nms_mask_kernel(const float* __restrict__ sOffB, const float* __restrict__ sArea,
                     unsigned long long* __restrict__ masks)
{
    __shared__ float jb0[64], jb1[64], jb2[64], jb3[64], ja[64];
    int jw = blockIdx.x;
    int it = blockIdx.y;
    int n  = blockIdx.z;
    int t = threadIdx.x;
    int jj = jw * 64 + t;
    const float* B = sOffB + (size_t)n * 5000 * 4;
    const float* A = sArea + (size_t)n * 5000;
    if (jj < 5000) {
        jb0[t] = B[jj * 4]; jb1[t] = B[jj * 4 + 1];
        jb2[t] = B[jj * 4 + 2]; jb3[t] = B[jj * 4 + 3];
        ja[t] = A[jj];
    } else {
        jb0[t] = -3e8f; jb1[t] = -3e8f; jb2[t] = -3e8f; jb3[t] = -3e8f; ja[t] = 0.f;
    }
    __syncthreads();
    int i = it * 64 + t;
    if (i >= 5000) return;
    float b0 = B[i * 4], b1 = B[i * 4 + 1], b2 = B[i * 4 + 2], b3 = B[i * 4 + 3];
    float ai = A[i];
    unsigned long long m = 0;
    for (int u = 0; u < 64; ++u) {
        float xx1 = fmaxf(b0, jb0[u]);
        float yy1 = fmaxf(b1, jb1[u]);
        float xx2 = fminf(b2, jb2[u]);
        float yy2 = fminf(b3, jb3[u]);
        float iw = fmaxf(xx2 - xx1, 0.f), ih = fmaxf(yy2 - yy1, 0.f);
        float inter = iw * ih;
        float iou = inter / (ai + ja[u] - inter + 1e-9f);
        if (iou > NMS_T) m |= (1ull << u);
    }
    masks[((size_t)n * 5000 + i) * 79 + jw] = m;
}

// ----------------------------------------------------------------------------
// NMS stage 2: serial greedy scan with early exit once 100 survivors found.
// Semantics identical to reference greedy NMS + top_k(where(keep,s,0),100).
// ----------------------------------------------------------------------------
__global__ __launch_bounds__(128)
void nms_scan_kernel(const unsigned long long* __restrict__ masks,
                     const float* __restrict__ sScore, const float* __restrict__ sBox,
                     const float* __restrict__ sCls, float* __restrict__ out)
{
    __shared__ unsigned long long rem[80];
    __shared__ int alive[100], dead[100];
    __shared__ int st[3];   // na, nd, aliveFlag
    int n = blockIdx.x, t = threadIdx.x;
    const float* S = sScore + (size_t)n * 5000;
    for (int i = t; i < 80; i += 128) rem[i] = 0ull;
    if (t == 0) { st[0] = 0; st[1] = 0; }
    __syncthreads();
    for (int i = 0; i < 5000; ++i) {
        if (t == 0) {
            bool sup = (rem[i >> 6] >> (i & 63)) & 1ull;
            float s = S[i];
            bool al = (!sup) && (s > 0.f);
            st[2] = al ? 1 : 0;
            if (al) { if (st[0] < 100) alive[st[0]] = i; st[0]++; }
            else    { if (st[1] < 100) dead[st[1]] = i;  st[1]++; }
        }
        __syncthreads();
        bool stop = (st[0] >= 100);
        if (st[2] && !stop) {
            const unsigned long long* row = masks + ((size_t)n * 5000 + i) * 79;
            if (t < 79) rem[t] |= row[t];
        }
        __syncthreads();
        if (stop) break;
    }
    __syncthreads();
    int na = st[0]; if (na > 100) na = 100;
    for (int r = t; r < 100; r += 128) {
        int p; float sc;
        if (r < na) { p = alive[r]; sc = S[p]; }
        else { p = dead[r - na]; sc = 0.f; }
        const float* bb = sBox + (((size_t)n * 5000) + p) * 4;
        out[(n * 100 + r) * 4 + 0] = bb[0];
        out[(n * 100 + r) * 4 + 1] = bb[1];
        out[(n * 100 + r) * 4 + 2] = bb[2];
        out[(n * 100 + r) * 4 + 3] = bb[3];
        out[800 + n * 100 + r] = sc;
        out[1000 + n * 100 + r] = sCls[(size_t)n * 5000 + p];
    }
}

// ----------------------------------------------------------------------------
extern "C" void kernel_launch(void* const* d_in, const int* in_sizes, int n_in,
                              void* d_out, int out_size, void* d_ws, size_t ws_size,
                              hipStream_t stream)
{
    const float* feat[5] = { (const float*)d_in[0], (const float*)d_in[1],
                             (const float*)d_in[2], (const float*)d_in[3],
                             (const float*)d_in[4] };
    const float* cls_w   = (const float*)d_in[5];
    const float* cls_b   = (const float*)d_in[6];
    const float* box_w   = (const float*)d_in[7];
    const float* box_b   = (const float*)d_in[8];
    const float* score_w = (const float*)d_in[9];
    const float* score_b = (const float*)d_in[10];
    const float* pred_w  = (const float*)d_in[11];
    const float* pred_b  = (const float*)d_in[12];
    const float* ctr_w   = (const float*)d_in[13];
    const float* ctr_b   = (const float*)d_in[14];

    char* ws = (char*)d_ws;
    size_t off = 0;
    auto alloc = [&](size_t nbytes) -> void* {
        void* p = ws + off;
        off += (nbytes + 255) & ~(size_t)255;
        return p;
    };
    const int HWmax = 128 * 168;
    float* ping   = (float*)alloc(sizeof(float) * 2 * 256 * (size_t)HWmax);
    float* pong   = (float*)alloc(sizeof(float) * 2 * 256 * (size_t)HWmax);
    float* lg81   = (float*)alloc(sizeof(float) * 2 * 81 * (size_t)HWmax);
    float* deltas = (float*)alloc(sizeof(float) * 2 * 4 * (size_t)HWmax);
    float* scores = (float*)alloc(sizeof(float) * 2 * (size_t)HWmax * 80);
    float* packw  = (float*)alloc(sizeof(float) * 81 * 2304);
    float* packb  = (float*)alloc(sizeof(float) * 256);
    unsigned* hist = (unsigned*)alloc(sizeof(unsigned) * 2 * 4096);
    int* sel       = (int*)alloc(sizeof(int) * 2 * 8);
    int* counters  = (int*)alloc(sizeof(int) * 2 * 2);
    unsigned* eqList = (unsigned*)alloc(sizeof(unsigned) * 2 * 4096);
    int* candIdx     = (int*)alloc(sizeof(int) * 2 * 5000);
    float* candScore = (float*)alloc(sizeof(float) * 2 * 5000);
    float* candZ     = (float*)alloc(sizeof(float) * 2 * 5000);
    float* candBox   = (float*)alloc(sizeof(float) * 2 * 5000 * 4);
    int* candCls     = (int*)alloc(sizeof(int) * 2 * 5000);
    float* sBox   = (float*)alloc(sizeof(float) * 2 * 5000 * 4);
    float* sScore = (float*)alloc(sizeof(float) * 2 * 5000);
    float* sCls   = (float*)alloc(sizeof(float) * 2 * 5000);
    float* sOffB  = (float*)alloc(sizeof(float) * 2 * 5000 * 4);
    float* sArea  = (float*)alloc(sizeof(float) * 2 * 5000);
    // NMS masks alias ping (free once all convs are done): 2*5000*79*8B = 6.3MB
    unsigned long long* masks = (unsigned long long*)ping;
    // lvl1-4 dual-tower buffers carve ping/pong halves (each half 22MB >= lvl1's 11MB)
    const size_t halfE = (size_t)256 * HWmax;  // elements per half (covers n=2 of lvl1)
    float* bufA0 = ping;
    float* bufA1 = ping + halfE;
    float* bufB0 = pong;
    float* bufB1 = pong + halfE;

    pack_kernel<<<(81 * 2304 + 255) / 256, 256, 0, stream>>>(score_w, score_b, ctr_w, ctr_b, packw, packb);

    const int   LH[5] = { 128, 64, 32, 16, 8 };
    const int   LW[5] = { 168, 84, 42, 21, 11 };
    const float LS[5] = { 8.f, 16.f, 32.f, 64.f, 128.f };
    const size_t WS = 589824;  // 256*256*9

    for (int lvl = 0; lvl < 5; ++lvl) {
        int H = LH[lvl], W = LW[lvl], HW = H * W;
        int tilesX = (W + 15) / 16, tilesY = (H + 7) / 8;
        int tiles = tilesX * tilesY;

        if (lvl == 0) {
            // big grids: sequential towers, ping/pong (4 z-chunks each)
            dim3 gT(tiles, 2, 4);
            conv_dual<1><<<gT, 256, 0, stream>>>(feat[0], feat[0], cls_w + 0 * WS, cls_w, cls_b + 0,   cls_b, ping, ping, H, W, 256, 256, 4, tilesX);
            conv_dual<1><<<gT, 256, 0, stream>>>(ping,    ping,    cls_w + 1 * WS, cls_w, cls_b + 256, cls_b, pong, pong, H, W, 256, 256, 4, tilesX);
            conv_dual<1><<<gT, 256, 0, stream>>>(pong,    pong,    cls_w + 2 * WS, cls_w, cls_b + 512, cls_b, ping, ping, H, W, 256, 256, 4, tilesX);
            conv_dual<1><<<gT, 256, 0, stream>>>(ping,    ping,    cls_w + 3 * WS, cls_w, cls_b + 768, cls_b, pong, pong, H, W, 256, 256, 4, tilesX);
            dim3 gL(tiles, 2, 2);
            conv_dual<0><<<gL, 256, 0, stream>>>(pong, pong, packw, packw, packb, packb, lg81, lg81, H, W, 81, 81, 2, tilesX);
            conv_dual<1><<<gT, 256, 0, stream>>>(feat[0], feat[0], box_w + 0 * WS, box_w, box_b + 0,   box_b, ping, ping, H, W, 256, 256, 4, tilesX);
            conv_dual<1><<<gT, 256, 0, stream>>>(ping,    ping,    box_w + 1 * WS, box_w, box_b + 256, box_b, pong, pong, H, W, 256, 256, 4, tilesX);
            conv_dual<1><<<gT, 256, 0, stream>>>(pong,    pong,    box_w + 2 * WS, box_w, box_b + 512, box_b, ping, ping, H, W, 256, 256, 4, tilesX);
            conv_dual<1><<<gT, 256, 0, stream>>>(ping,    ping,    box_w + 3 * WS, box_w, box_b + 768, box_b, pong, pong, H, W, 256, 256, 4, tilesX);
            dim3 gD(tiles, 2, 1);
            conv_dual<0><<<gD, 256, 0, stream>>>(pong, pong, pred_w, pred_w, pred_b, pred_b, deltas, deltas, H, W, 4, 4, 1, tilesX);
        } else {
            // small grids: dual-tower merged dispatches (z = 8), halves of ping/pong
            dim3 gT(tiles, 2, 8);
            conv_dual<1><<<gT, 256, 0, stream>>>(feat[lvl], feat[lvl], cls_w + 0 * WS, box_w + 0 * WS, cls_b + 0,   box_b + 0,   bufA0, bufB0, H, W, 256, 256, 4, tilesX);
            conv_dual<1><<<gT, 256, 0, stream>>>(bufA0,     bufB0,     cls_w + 1 * WS, box_w + 1 * WS, cls_b + 256, box_b + 256, bufA1, bufB1, H, W, 256, 256, 4, tilesX);
            conv_dual<1><<<gT, 256, 0, stream>>>(bufA1,     bufB1,     cls_w + 2 * WS, box_w + 2 * WS, cls_b + 512, box_b + 512, bufA0, bufB0, H, W, 256, 256, 4, tilesX);
            conv_dual<1><<<gT, 256, 0, stream>>>(bufA0,     bufB0,     cls_w + 3 * WS, box_w + 3 * WS, cls_b + 768, box_b + 768, bufA1, bufB1, H, W, 256, 256, 4, tilesX);
            dim3 gH2(tiles, 2, 3);
            conv_dual<0><<<gH2, 256, 0, stream>>>(bufA1, bufB1, packw, pred_w, packb, pred_b, lg81, deltas, H, W, 81, 4, 2, tilesX);
        }

        dim3 gS((HW + 63) / 64, 2);
        score_kernel<<<gS, 256, 0, stream>>>(lg81, scores, HW);
        int nel = HW * 80;
        int hb = (nel + 255) / 256; if (hb > 512) hb = 512;
        dim3 gHist(hb, 2);
        hipMemsetAsync(hist, 0, 2 * 4096 * sizeof(unsigned), stream);
        hist_kernel<<<gHist, 256, 0, stream>>>(scores, hist, sel, nel, 0);
        scan_kernel<<<2, 1024, 0, stream>>>(hist, sel, 0);
        hipMemsetAsync(hist, 0, 2 * 4096 * sizeof(unsigned), stream);
        hist_kernel<<<gHist, 256, 0, stream>>>(scores, hist, sel, nel, 1);
        scan_kernel<<<2, 1024, 0, stream>>>(hist, sel, 1);
        hipMemsetAsync(hist, 0, 2 * 4096 * sizeof(unsigned), stream);
        hist_kernel<<<gHist, 256, 0, stream>>>(scores, hist, sel, nel, 2);
        scan_kernel<<<2, 1024, 0, stream>>>(hist, sel, 2);
        hipMemsetAsync(counters, 0, 2 * 2 * sizeof(int), stream);
        compact_kernel<<<gHist, 256, 0, stream>>>(scores, nel, sel, candIdx, candScore, eqList, counters, lvl);
        eqfinish_kernel<<<2, 256, 0, stream>>>(eqList, sel, counters, candIdx, candScore, lvl);
        lvlsort_kernel<<<2, 256, 0, stream>>>(candIdx, candScore, lvl);
        decode_kernel<<<(2 * KTOP + 255) / 256, 256, 0, stream>>>(candIdx, candScore, deltas,
                                                                  candBox, candZ, candCls,
                                                                  HW, W, lvl, LS[lvl]);
    }
    gsort_kernel<<<2, 1024, 0, stream>>>(candZ, candBox, candCls, sBox, sScore, sCls, sOffB, sArea);
    // NMS: parallel masks (ping is free now) + early-exit serial scan
    dim3 gM(79, 79, 2);
    nms_mask_kernel<<<gM, 64, 0, stream>>>(sOffB, sArea, masks);
    nms_scan_kernel<<<2, 128, 0, stream>>>(masks, sScore, sBox, sCls, (float*)d_out);
}